// Round 4
// baseline (457.087 us; speedup 1.0000x reference)
//
#include <hip/hip_runtime.h>

#define BS 256
#define NS 24   // candidate slots: 4 c1-corners, 4 c2-corners, 16 "intersections"

// ---- compile-time Batcher merge-exchange network for n=24 (Knuth 5.2.2M) ----
struct CEp { int a, b; };
struct CEList { CEp p[160]; int n; };
constexpr CEList make_ce() {
    CEList L{}; L.n = 0;
    const int n = NS;
    int t = 0; while ((1 << t) < n) t++;          // t = 5
    for (int p = 1 << (t - 1); p > 0; p >>= 1) {
        int q = 1 << (t - 1), r = 0, d = p;
        for (;;) {
            for (int i = 0; i < n - d; i++)
                if ((i & p) == r) { L.p[L.n].a = i; L.p[L.n].b = i + d; L.n++; }
            if (q == p) break;
            d = q - p; q >>= 1; r = p;
        }
    }
    return L;   // 127 comparators for n=24
}
constexpr CEList CEL = make_ce();

__device__ __forceinline__ float rcpf(float x) { return __builtin_amdgcn_rcpf(x); }

// Stable ascending sort of 4 (x,y) pairs by x (counting-rank; all static indexing).
__device__ __forceinline__ void sort4_by_x(const float* x, const float* y,
                                           float* sx, float* sy) {
    int rk[4];
#pragma unroll
    for (int a = 0; a < 4; a++) {
        int r = 0;
#pragma unroll
        for (int b = 0; b < 4; b++)
            r += (x[b] < x[a]) || (x[b] == x[a] && b < a);
        rk[a] = r;
    }
#pragma unroll
    for (int r = 0; r < 4; r++) {
        float vx = 0.f, vy = 0.f;
#pragma unroll
        for (int a = 0; a < 4; a++)
            if (rk[a] == r) { vx = x[a]; vy = y[a]; }
        sx[r] = vx; sy[r] = vy;
    }
}

__global__ __launch_bounds__(BS, 2)
void fpdiou_kernel(const float* __restrict__ pred, const float* __restrict__ tgt,
                   float* __restrict__ out, int n, float inv_n)
{
    __shared__ float s_red[BS / 64];
    const int tid = threadIdx.x;
    const int i = blockIdx.x * BS + tid;
    float loss = 0.f;

    if (i < n) {
        const float* pp = pred + (size_t)i * 5;
        const float* gg = tgt  + (size_t)i * 5;
        const float p0 = pp[0], p1 = pp[1], pw = pp[2], ph = pp[3], pa = pp[4];
        const float g0 = gg[0], g1 = gg[1], gw = gg[2], gh = gg[3], ga = gg[4];

        float s1, co1, s2, co2;
        sincosf(pa, &s1, &co1);
        sincosf(ga, &s2, &co2);

        const float DX[4] = {0.5f, -0.5f, -0.5f, 0.5f};
        const float DY[4] = {0.5f,  0.5f, -0.5f, -0.5f};
        float c1x[4], c1y[4], c2x[4], c2y[4];
#pragma unroll
        for (int q = 0; q < 4; q++) {
            float dx = DX[q] * pw, dy = DY[q] * ph;
            c1x[q] = dx * co1 - dy * s1 + p0;
            c1y[q] = dx * s1 + dy * co1 + p1;
            dx = DX[q] * gw; dy = DY[q] * gh;
            c2x[q] = dx * co2 - dy * s2 + g0;
            c2y[q] = dx * s2 + dy * co2 + g1;
        }

        // ---- FPDIoU distance term ----
        float res;
        {
            float psx[4], psy[4], gsx[4], gsy[4];
            sort4_by_x(c1x, c1y, psx, psy);
            sort4_by_x(c2x, c2y, gsx, gsy);
            const float d0 = gsx[0] - psx[0];
            float d = 2.f * d0 * d0;
#pragma unroll
            for (int q = 1; q < 4; q++) {
                const float dxq = psx[q] - gsx[q];
                const float dyq = psy[q] - gsy[q];
                d += dxq * dxq + dyq * dyq;
            }
            res = d * (1.f / 4194304.f);
        }

        // ---- fill 24 fixed slots (coords in VGPRs, validity bitmask) ----
        float wx[NS], wy[NS];
        unsigned vm = 0;
        float sx = 0.f, sy = 0.f;
        int k = 0;

        // slots 0..3: c1 corners inside box2
        {
            const float ax = c2x[0], ay = c2y[0];
            const float abx = c2x[1] - ax, aby = c2y[1] - ay;
            const float adx = c2x[3] - ax, ady = c2y[3] - ay;
            const float idab = rcpf(abx * abx + aby * aby);
            const float idad = rcpf(adx * adx + ady * ady);
#pragma unroll
            for (int q = 0; q < 4; q++) {
                const float amx = c1x[q] - ax, amy = c1y[q] - ay;
                const float pab = (abx * amx + aby * amy) * idab;
                const float pd  = (adx * amx + ady * amy) * idad;
                const float e = 1e-6f;
                const bool m = (pab > -e) & (pab < 1.f + e) & (pd > -e) & (pd < 1.f + e);
                wx[q] = c1x[q]; wy[q] = c1y[q];
                if (m) { vm |= 1u << q; sx += c1x[q]; sy += c1y[q]; k++; }
            }
        }
        // slots 4..7: c2 corners inside box1
        {
            const float ax = c1x[0], ay = c1y[0];
            const float abx = c1x[1] - ax, aby = c1y[1] - ay;
            const float adx = c1x[3] - ax, ady = c1y[3] - ay;
            const float idab = rcpf(abx * abx + aby * aby);
            const float idad = rcpf(adx * adx + ady * ady);
#pragma unroll
            for (int q = 0; q < 4; q++) {
                const float amx = c2x[q] - ax, amy = c2y[q] - ay;
                const float pab = (abx * amx + aby * amy) * idab;
                const float pd  = (adx * amx + ady * amy) * idad;
                const float e = 1e-6f;
                const bool m = (pab > -e) & (pab < 1.f + e) & (pd > -e) & (pd < 1.f + e);
                wx[4 + q] = c2x[q]; wy[4 + q] = c2y[q];
                if (m) { vm |= 1u << (4 + q); sx += c2x[q]; sy += c2y[q]; k++; }
            }
        }
        // slots 8..23: reference's quirky "intersections" (t in (0,1), u = -den_u/num in (0,1))
#pragma unroll
        for (int a = 0; a < 4; a++) {
            const float x1 = c1x[a], y1 = c1y[a];
            const float ex = c1x[(a + 1) & 3] - x1, ey = c1y[(a + 1) & 3] - y1;
#pragma unroll
            for (int b = 0; b < 4; b++) {
                const float x3 = c2x[b], y3 = c2y[b];
                const float fx = c2x[(b + 1) & 3] - x3, fy = c2y[(b + 1) & 3] - y3;
                const float num = fy * ex - fx * ey;
                const float dx13 = x1 - x3, dy13 = y1 - y3;
                const float den_t = fx * dy13 - fy * dx13;
                const float den_u = ex * dy13 - ey * dx13;
                const float rn = rcpf(num);          // num==0 -> inf/nan -> cmp false
                const float t = den_t * rn;
                const float u = -den_u * rn;         // reference's (sign-flipped) u
                const bool m = (t > 0.f) & (t < 1.f) & (u > 0.f) & (u < 1.f);
                const float t2 = den_t * rcpf(num + 1e-8f);   // reference quirk
                const float ix = x1 + t2 * ex, iy = y1 + t2 * ey;
                const int s = 8 + a * 4 + b;
                wx[s] = m ? ix : 0.f;                // pts * mask, like reference
                wy[s] = m ? iy : 0.f;
                if (m) { vm |= 1u << s; sx += ix; sy += iy; k++; }
            }
        }

        // ---- sort keys: monotone-u32(pseudo-angle), invalid -> 1e9 ----
        const float ik = 1.f / (float)(k > 0 ? k : 1);
        const float mx = sx * ik, my = sy * ik;
        unsigned key[NS];
#pragma unroll
        for (int s = 0; s < NS; s++) {
            const float dx = wx[s] - mx, dy = wy[s] - my;
            const float sa = fabsf(dx) + fabsf(dy);
            const float r = (sa == 0.f) ? 0.f : (1.f - dx * rcpf(sa));
            float ang = copysignf(r, dy) + 0.0f;     // +0.0f canonicalizes -0 -> +0
            const bool m = (vm >> s) & 1u;
            ang = m ? ang : 1e9f;
            unsigned bbits = __float_as_uint(ang);
            bbits ^= (unsigned)((int)bbits >> 31) | 0x80000000u;   // monotone map
            key[s] = bbits;
        }

        // ---- Batcher network: sort (key, x, y) ascending, branchless ----
#pragma unroll
        for (int c = 0; c < CEL.n; c++) {
            const int A = CEL.p[c].a, B = CEL.p[c].b;
            const bool sw = key[B] < key[A];
            const unsigned ka = sw ? key[B] : key[A];
            const unsigned kb = sw ? key[A] : key[B];
            key[A] = ka; key[B] = kb;
            const float xa = sw ? wx[B] : wx[A];
            const float xb = sw ? wx[A] : wx[B];
            wx[A] = xa; wx[B] = xb;
            const float ya = sw ? wy[B] : wy[A];
            const float yb = sw ? wy[A] : wy[B];
            wy[A] = ya; wy[B] = yb;
        }

        // ---- masked shoelace over first k sorted vertices (wrap k-1 -> 0) ----
        float cr = 0.f;
#pragma unroll
        for (int j = 0; j < NS; j++) {
            const int jn = (j + 1 < NS) ? j + 1 : 0;   // compile-time safe index
            const bool nw = (j + 1 < k);
            const float nx = nw ? wx[jn] : wx[0];
            const float ny = nw ? wy[jn] : wy[0];
            const float crj = wx[j] * ny - wy[j] * nx;
            cr += (j < k) ? crj : 0.f;
        }
        const float area = fabsf(cr) * 0.5f;

        // ---- IoU + loss ----
        const float a1 = pw * ph, a2 = gw * gh;
        float iou = area / (a1 + a2 - area);
        iou = fmaxf(iou, 1e-6f);
        loss = 1.f - iou + res;
    }

    // ---- block reduction: wave shuffle -> LDS -> one atomic per block ----
#pragma unroll
    for (int off = 32; off > 0; off >>= 1)
        loss += __shfl_down(loss, off, 64);
    if ((tid & 63) == 0) s_red[tid >> 6] = loss;
    __syncthreads();
    if (tid == 0) {
        float t = 0.f;
#pragma unroll
        for (int w = 0; w < BS / 64; w++) t += s_red[w];
        atomicAdd(out, t * inv_n);
    }
}

extern "C" void kernel_launch(void* const* d_in, const int* in_sizes, int n_in,
                              void* d_out, int out_size, void* d_ws, size_t ws_size,
                              hipStream_t stream)
{
    const float* pred = (const float*)d_in[0];
    const float* tgt  = (const float*)d_in[1];
    float* out = (float*)d_out;
    const int n = in_sizes[0] / 5;
    const int nblk = (n + BS - 1) / BS;

    hipMemsetAsync(out, 0, sizeof(float), stream);   // async on stream: capturable
    fpdiou_kernel<<<nblk, BS, 0, stream>>>(pred, tgt, out, n, 1.f / (float)n);
}

// Round 5
// 132.473 us; speedup vs baseline: 3.4504x; 3.4504x over previous
//
#include <hip/hip_runtime.h>

#define BS 256
#define NS 24   // candidate slots: 4 c1-corners, 4 c2-corners, 16 "intersections"

__device__ __forceinline__ float rcpf(float x) { return __builtin_amdgcn_rcpf(x); }

// Stable ascending sort of 4 (x,y) pairs by x (counting-rank; all static indexing).
__device__ __forceinline__ void sort4_by_x(const float* x, const float* y,
                                           float* sx, float* sy) {
    int rk[4];
#pragma unroll
    for (int a = 0; a < 4; a++) {
        int r = 0;
#pragma unroll
        for (int b = 0; b < 4; b++)
            r += (x[b] < x[a]) || (x[b] == x[a] && b < a);
        rk[a] = r;
    }
#pragma unroll
    for (int r = 0; r < 4; r++) {
        float vx = 0.f, vy = 0.f;
#pragma unroll
        for (int a = 0; a < 4; a++)
            if (rk[a] == r) { vx = x[a]; vy = y[a]; }
        sx[r] = vx; sy[r] = vy;
    }
}

// Compare-exchange with LITERAL indices -> SROA-promotable (the round-4 lesson:
// indices loaded from a constexpr table at runtime force the arrays to scratch).
#define CSWAP(A, B) do {                                          \
    const unsigned ka_ = key[A], kb_ = key[B];                    \
    const bool sw_ = kb_ < ka_;                                   \
    key[A] = sw_ ? kb_ : ka_;  key[B] = sw_ ? ka_ : kb_;          \
    const float xa_ = wx[A], xb_ = wx[B];                         \
    wx[A] = sw_ ? xb_ : xa_;   wx[B] = sw_ ? xa_ : xb_;           \
    const float ya_ = wy[A], yb_ = wy[B];                         \
    wy[A] = sw_ ? yb_ : ya_;   wy[B] = sw_ ? ya_ : yb_;           \
} while (0)

__global__ __launch_bounds__(BS, 2)
void fpdiou_kernel(const float* __restrict__ pred, const float* __restrict__ tgt,
                   float* __restrict__ out, int n, float inv_n)
{
    __shared__ float s_red[BS / 64];
    const int tid = threadIdx.x;
    const int i = blockIdx.x * BS + tid;
    float loss = 0.f;

    if (i < n) {
        const float* pp = pred + (size_t)i * 5;
        const float* gg = tgt  + (size_t)i * 5;
        const float p0 = pp[0], p1 = pp[1], pw = pp[2], ph = pp[3], pa = pp[4];
        const float g0 = gg[0], g1 = gg[1], gw = gg[2], gh = gg[3], ga = gg[4];

        float s1, co1, s2, co2;
        sincosf(pa, &s1, &co1);
        sincosf(ga, &s2, &co2);

        const float DX[4] = {0.5f, -0.5f, -0.5f, 0.5f};
        const float DY[4] = {0.5f,  0.5f, -0.5f, -0.5f};
        float c1x[4], c1y[4], c2x[4], c2y[4];
#pragma unroll
        for (int q = 0; q < 4; q++) {
            float dx = DX[q] * pw, dy = DY[q] * ph;
            c1x[q] = dx * co1 - dy * s1 + p0;
            c1y[q] = dx * s1 + dy * co1 + p1;
            dx = DX[q] * gw; dy = DY[q] * gh;
            c2x[q] = dx * co2 - dy * s2 + g0;
            c2y[q] = dx * s2 + dy * co2 + g1;
        }

        // ---- FPDIoU distance term ----
        float res;
        {
            float psx[4], psy[4], gsx[4], gsy[4];
            sort4_by_x(c1x, c1y, psx, psy);
            sort4_by_x(c2x, c2y, gsx, gsy);
            const float d0 = gsx[0] - psx[0];
            float d = 2.f * d0 * d0;
#pragma unroll
            for (int q = 1; q < 4; q++) {
                const float dxq = psx[q] - gsx[q];
                const float dyq = psy[q] - gsy[q];
                d += dxq * dxq + dyq * dyq;
            }
            res = d * (1.f / 4194304.f);
        }

        // ---- fill 24 fixed slots (VGPR arrays, validity bitmask) ----
        float wx[NS], wy[NS];
        unsigned vm = 0;
        float sx = 0.f, sy = 0.f;
        int k = 0;

        // slots 0..3: c1 corners inside box2
        {
            const float ax = c2x[0], ay = c2y[0];
            const float abx = c2x[1] - ax, aby = c2y[1] - ay;
            const float adx = c2x[3] - ax, ady = c2y[3] - ay;
            const float idab = rcpf(abx * abx + aby * aby);
            const float idad = rcpf(adx * adx + ady * ady);
#pragma unroll
            for (int q = 0; q < 4; q++) {
                const float amx = c1x[q] - ax, amy = c1y[q] - ay;
                const float pab = (abx * amx + aby * amy) * idab;
                const float pd  = (adx * amx + ady * amy) * idad;
                const float e = 1e-6f;
                const bool m = (pab > -e) & (pab < 1.f + e) & (pd > -e) & (pd < 1.f + e);
                wx[q] = c1x[q]; wy[q] = c1y[q];
                if (m) { vm |= 1u << q; sx += c1x[q]; sy += c1y[q]; k++; }
            }
        }
        // slots 4..7: c2 corners inside box1
        {
            const float ax = c1x[0], ay = c1y[0];
            const float abx = c1x[1] - ax, aby = c1y[1] - ay;
            const float adx = c1x[3] - ax, ady = c1y[3] - ay;
            const float idab = rcpf(abx * abx + aby * aby);
            const float idad = rcpf(adx * adx + ady * ady);
#pragma unroll
            for (int q = 0; q < 4; q++) {
                const float amx = c2x[q] - ax, amy = c2y[q] - ay;
                const float pab = (abx * amx + aby * amy) * idab;
                const float pd  = (adx * amx + ady * amy) * idad;
                const float e = 1e-6f;
                const bool m = (pab > -e) & (pab < 1.f + e) & (pd > -e) & (pd < 1.f + e);
                wx[4 + q] = c2x[q]; wy[4 + q] = c2y[q];
                if (m) { vm |= 1u << (4 + q); sx += c2x[q]; sy += c2y[q]; k++; }
            }
        }
        // slots 8..23: reference's quirky "intersections" (t in (0,1), u = -den_u/num)
#pragma unroll
        for (int a = 0; a < 4; a++) {
            const float x1 = c1x[a], y1 = c1y[a];
            const float ex = c1x[(a + 1) & 3] - x1, ey = c1y[(a + 1) & 3] - y1;
#pragma unroll
            for (int b = 0; b < 4; b++) {
                const float x3 = c2x[b], y3 = c2y[b];
                const float fx = c2x[(b + 1) & 3] - x3, fy = c2y[(b + 1) & 3] - y3;
                const float num = fy * ex - fx * ey;
                const float dx13 = x1 - x3, dy13 = y1 - y3;
                const float den_t = fx * dy13 - fy * dx13;
                const float den_u = ex * dy13 - ey * dx13;
                const float rn = rcpf(num);          // num==0 -> inf -> cmp false
                const float t = den_t * rn;
                const float u = -den_u * rn;         // reference's (sign-flipped) u
                const bool m = (t > 0.f) & (t < 1.f) & (u > 0.f) & (u < 1.f);
                const float t2 = den_t * rcpf(num + 1e-8f);   // reference quirk
                const float ix = x1 + t2 * ex, iy = y1 + t2 * ey;
                const int s = 8 + a * 4 + b;
                wx[s] = ix;                // garbage if invalid: key=1e9 sorts it
                wy[s] = iy;                // behind position k-1, never read
                if (m) { vm |= 1u << s; sx += ix; sy += iy; k++; }
            }
        }

        // ---- sort keys: monotone-u32(pseudo-angle), invalid -> 1e9 ----
        const float ik = 1.f / (float)(k > 0 ? k : 1);
        const float mx = sx * ik, my = sy * ik;
        unsigned key[NS];
#pragma unroll
        for (int s = 0; s < NS; s++) {
            const float dx = wx[s] - mx, dy = wy[s] - my;
            const float sa = fabsf(dx) + fabsf(dy);
            const float r = (sa == 0.f) ? 0.f : (1.f - dx * rcpf(sa));
            float ang = copysignf(r, dy) + 0.0f;     // canonicalize -0 -> +0
            const bool m = (vm >> s) & 1u;
            ang = m ? ang : 1e9f;
            unsigned bbits = __float_as_uint(ang);
            bbits ^= (unsigned)((int)bbits >> 31) | 0x80000000u;   // monotone map
            key[s] = bbits;
        }

        // ---- Batcher merge-exchange network, n=24 (127 comparators), literal idx ----
        // p=16
        CSWAP(0,16); CSWAP(1,17); CSWAP(2,18); CSWAP(3,19);
        CSWAP(4,20); CSWAP(5,21); CSWAP(6,22); CSWAP(7,23);
        // p=8
        CSWAP(0,8);  CSWAP(1,9);  CSWAP(2,10); CSWAP(3,11);
        CSWAP(4,12); CSWAP(5,13); CSWAP(6,14); CSWAP(7,15);
        CSWAP(8,16); CSWAP(9,17); CSWAP(10,18); CSWAP(11,19);
        CSWAP(12,20); CSWAP(13,21); CSWAP(14,22); CSWAP(15,23);
        // p=4
        CSWAP(0,4);  CSWAP(1,5);  CSWAP(2,6);  CSWAP(3,7);
        CSWAP(8,12); CSWAP(9,13); CSWAP(10,14); CSWAP(11,15);
        CSWAP(16,20); CSWAP(17,21); CSWAP(18,22); CSWAP(19,23);
        CSWAP(4,16); CSWAP(5,17); CSWAP(6,18); CSWAP(7,19);
        CSWAP(4,8);  CSWAP(5,9);  CSWAP(6,10); CSWAP(7,11);
        CSWAP(12,16); CSWAP(13,17); CSWAP(14,18); CSWAP(15,19);
        // p=2
        CSWAP(0,2);  CSWAP(1,3);  CSWAP(4,6);  CSWAP(5,7);
        CSWAP(8,10); CSWAP(9,11); CSWAP(12,14); CSWAP(13,15);
        CSWAP(16,18); CSWAP(17,19); CSWAP(20,22); CSWAP(21,23);
        CSWAP(2,16); CSWAP(3,17); CSWAP(6,20); CSWAP(7,21);
        CSWAP(2,8);  CSWAP(3,9);  CSWAP(6,12); CSWAP(7,13);
        CSWAP(10,16); CSWAP(11,17); CSWAP(14,20); CSWAP(15,21);
        CSWAP(2,4);  CSWAP(3,5);  CSWAP(6,8);  CSWAP(7,9);
        CSWAP(10,12); CSWAP(11,13); CSWAP(14,16); CSWAP(15,17);
        CSWAP(18,20); CSWAP(19,21);
        // p=1
        CSWAP(0,1);  CSWAP(2,3);  CSWAP(4,5);  CSWAP(6,7);
        CSWAP(8,9);  CSWAP(10,11); CSWAP(12,13); CSWAP(14,15);
        CSWAP(16,17); CSWAP(18,19); CSWAP(20,21); CSWAP(22,23);
        CSWAP(1,16); CSWAP(3,18); CSWAP(5,20); CSWAP(7,22);
        CSWAP(1,8);  CSWAP(3,10); CSWAP(5,12); CSWAP(7,14);
        CSWAP(9,16); CSWAP(11,18); CSWAP(13,20); CSWAP(15,22);
        CSWAP(1,4);  CSWAP(3,6);  CSWAP(5,8);  CSWAP(7,10);
        CSWAP(9,12); CSWAP(11,14); CSWAP(13,16); CSWAP(15,18);
        CSWAP(17,20); CSWAP(19,22);
        CSWAP(1,2);  CSWAP(3,4);  CSWAP(5,6);  CSWAP(7,8);
        CSWAP(9,10); CSWAP(11,12); CSWAP(13,14); CSWAP(15,16);
        CSWAP(17,18); CSWAP(19,20); CSWAP(21,22);

        // ---- masked shoelace over first k sorted vertices (wrap k-1 -> 0) ----
        float cr = 0.f;
#pragma unroll
        for (int j = 0; j < NS; j++) {
            const int jn = (j + 1 < NS) ? j + 1 : 0;   // compile-time index
            const bool nw = (j + 1 < k);
            const float nx = nw ? wx[jn] : wx[0];
            const float ny = nw ? wy[jn] : wy[0];
            const float crj = wx[j] * ny - wy[j] * nx;
            cr += (j < k) ? crj : 0.f;
        }
        const float area = fabsf(cr) * 0.5f;

        // ---- IoU + loss ----
        const float a1 = pw * ph, a2 = gw * gh;
        float iou = area / (a1 + a2 - area);
        iou = fmaxf(iou, 1e-6f);
        loss = 1.f - iou + res;
    }

    // ---- block reduction: wave shuffle -> LDS -> one atomic per block ----
#pragma unroll
    for (int off = 32; off > 0; off >>= 1)
        loss += __shfl_down(loss, off, 64);
    if ((tid & 63) == 0) s_red[tid >> 6] = loss;
    __syncthreads();
    if (tid == 0) {
        float t = 0.f;
#pragma unroll
        for (int w = 0; w < BS / 64; w++) t += s_red[w];
        atomicAdd(out, t * inv_n);
    }
}

extern "C" void kernel_launch(void* const* d_in, const int* in_sizes, int n_in,
                              void* d_out, int out_size, void* d_ws, size_t ws_size,
                              hipStream_t stream)
{
    const float* pred = (const float*)d_in[0];
    const float* tgt  = (const float*)d_in[1];
    float* out = (float*)d_out;
    const int n = in_sizes[0] / 5;
    const int nblk = (n + BS - 1) / BS;

    hipMemsetAsync(out, 0, sizeof(float), stream);   // async on stream: capturable
    fpdiou_kernel<<<nblk, BS, 0, stream>>>(pred, tgt, out, n, 1.f / (float)n);
}

// Round 6
// 132.134 us; speedup vs baseline: 3.4593x; 1.0026x over previous
//
#include <hip/hip_runtime.h>

#define BS 256
#define NS 24   // candidate slots: 4 c1-corners, 4 c2-corners, 16 "intersections"

__device__ __forceinline__ float rcpf(float x) { return __builtin_amdgcn_rcpf(x); }

// Key-only compare-exchange: v_min_u32 + v_max_u32, literal indices only
// (round-4 lesson: runtime indices -> scratch).
#define CSWAPK(A, B) do {                                         \
    const unsigned ka_ = key[A], kb_ = key[B];                    \
    key[A] = ka_ < kb_ ? ka_ : kb_;                               \
    key[B] = ka_ < kb_ ? kb_ : ka_;                               \
} while (0)

// (x,y) compare-exchange by x, literal indices (ties measure-zero: stability N/A)
#define CSW2(x, y, I, J) do {                                     \
    const bool sw_ = (x[J] < x[I]);                               \
    const float xi_ = x[I], xj_ = x[J], yi_ = y[I], yj_ = y[J];   \
    x[I] = sw_ ? xj_ : xi_;  x[J] = sw_ ? xi_ : xj_;              \
    y[I] = sw_ ? yj_ : yi_;  y[J] = sw_ ? yi_ : yj_;              \
} while (0)

__global__ __launch_bounds__(BS, 3)
void fpdiou_kernel(const float* __restrict__ pred, const float* __restrict__ tgt,
                   float* __restrict__ out, int n, float inv_n)
{
    // [slot][tid] float2 columns: per-thread private, stride BS*8 -> lane i hits
    // banks (2i,2i+1)%32 independent of slot: conflict-free b64, no barriers.
    __shared__ float2 s_v[NS * BS];
    __shared__ float s_red[BS / 64];

    const int tid = threadIdx.x;
    const int i = blockIdx.x * BS + tid;
    float loss = 0.f;

    if (i < n) {
        const float* pp = pred + (size_t)i * 5;
        const float* gg = tgt  + (size_t)i * 5;
        const float p0 = pp[0], p1 = pp[1], pw = pp[2], ph = pp[3], pa = pp[4];
        const float g0 = gg[0], g1 = gg[1], gw = gg[2], gh = gg[3], ga = gg[4];

        // native trig: |angle| <= ~2 rad, hw accuracy ~1e-6 abs — mean-safe
        const float s1 = __sinf(pa), co1 = __cosf(pa);
        const float s2 = __sinf(ga), co2 = __cosf(ga);

        const float DX[4] = {0.5f, -0.5f, -0.5f, 0.5f};
        const float DY[4] = {0.5f,  0.5f, -0.5f, -0.5f};
        float c1x[4], c1y[4], c2x[4], c2y[4];
#pragma unroll
        for (int q = 0; q < 4; q++) {
            float dx = DX[q] * pw, dy = DY[q] * ph;
            c1x[q] = dx * co1 - dy * s1 + p0;
            c1y[q] = dx * s1 + dy * co1 + p1;
            dx = DX[q] * gw; dy = DY[q] * gh;
            c2x[q] = dx * co2 - dy * s2 + g0;
            c2y[q] = dx * s2 + dy * co2 + g1;
        }

        // ---- FPDIoU distance term: 5-comparator sort-by-x networks ----
        float res;
        {
            float px_[4] = {c1x[0], c1x[1], c1x[2], c1x[3]};
            float py_[4] = {c1y[0], c1y[1], c1y[2], c1y[3]};
            float gx_[4] = {c2x[0], c2x[1], c2x[2], c2x[3]};
            float gy_[4] = {c2y[0], c2y[1], c2y[2], c2y[3]};
            CSW2(px_, py_, 0, 1); CSW2(px_, py_, 2, 3);
            CSW2(px_, py_, 0, 2); CSW2(px_, py_, 1, 3); CSW2(px_, py_, 1, 2);
            CSW2(gx_, gy_, 0, 1); CSW2(gx_, gy_, 2, 3);
            CSW2(gx_, gy_, 0, 2); CSW2(gx_, gy_, 1, 3); CSW2(gx_, gy_, 1, 2);
            const float d0 = gx_[0] - px_[0];
            float d = 2.f * d0 * d0;
#pragma unroll
            for (int q = 1; q < 4; q++) {
                const float dxq = px_[q] - gx_[q];
                const float dyq = py_[q] - gy_[q];
                d += dxq * dxq + dyq * dyq;
            }
            res = d * (1.f / 4194304.f);
        }

        // ---- fill 24 slots: coords -> LDS (static offsets), validity bitmask ----
        unsigned vm = 0;
        float sx = 0.f, sy = 0.f;
        int k = 0;
        const float e = 1e-6f;

        // slots 0..3: c1 corners inside box2 (division-free threshold form)
        {
            const float ax = c2x[0], ay = c2y[0];
            const float abx = c2x[1] - ax, aby = c2y[1] - ay;
            const float adx = c2x[3] - ax, ady = c2y[3] - ay;
            const float dab = abx * abx + aby * aby;
            const float dad = adx * adx + ady * ady;
            const float lo_ab = -e * dab, hi_ab = (1.f + e) * dab;
            const float lo_ad = -e * dad, hi_ad = (1.f + e) * dad;
#pragma unroll
            for (int q = 0; q < 4; q++) {
                const float amx = c1x[q] - ax, amy = c1y[q] - ay;
                const float dot_ab = abx * amx + aby * amy;
                const float dot_ad = adx * amx + ady * amy;
                const bool m = (dot_ab > lo_ab) & (dot_ab < hi_ab)
                             & (dot_ad > lo_ad) & (dot_ad < hi_ad);
                s_v[q * BS + tid] = make_float2(c1x[q], c1y[q]);
                if (m) { vm |= 1u << q; sx += c1x[q]; sy += c1y[q]; k++; }
            }
        }
        // slots 4..7: c2 corners inside box1
        {
            const float ax = c1x[0], ay = c1y[0];
            const float abx = c1x[1] - ax, aby = c1y[1] - ay;
            const float adx = c1x[3] - ax, ady = c1y[3] - ay;
            const float dab = abx * abx + aby * aby;
            const float dad = adx * adx + ady * ady;
            const float lo_ab = -e * dab, hi_ab = (1.f + e) * dab;
            const float lo_ad = -e * dad, hi_ad = (1.f + e) * dad;
#pragma unroll
            for (int q = 0; q < 4; q++) {
                const float amx = c2x[q] - ax, amy = c2y[q] - ay;
                const float dot_ab = abx * amx + aby * amy;
                const float dot_ad = adx * amx + ady * amy;
                const bool m = (dot_ab > lo_ab) & (dot_ab < hi_ab)
                             & (dot_ad > lo_ad) & (dot_ad < hi_ad);
                s_v[(4 + q) * BS + tid] = make_float2(c2x[q], c2y[q]);
                if (m) { vm |= 1u << (4 + q); sx += c2x[q]; sy += c2y[q]; k++; }
            }
        }
        // slots 8..23: reference's quirky "intersections".
        // t = den_t/num in (0,1)  <=>  den_t*num>0 && |den_t|<|num|
        // u = -den_u/num in (0,1) <=>  den_u*num<0 && |den_u|<|num|
        // num==0 -> products are +-0 -> strict cmps false (matches ref's t=-1).
#pragma unroll
        for (int a = 0; a < 4; a++) {
            const float x1 = c1x[a], y1 = c1y[a];
            const float ex = c1x[(a + 1) & 3] - x1, ey = c1y[(a + 1) & 3] - y1;
#pragma unroll
            for (int b = 0; b < 4; b++) {
                const float x3 = c2x[b], y3 = c2y[b];
                const float fx = c2x[(b + 1) & 3] - x3, fy = c2y[(b + 1) & 3] - y3;
                const float num = fy * ex - fx * ey;
                const float dx13 = x1 - x3, dy13 = y1 - y3;
                const float den_t = fx * dy13 - fy * dx13;
                const float den_u = ex * dy13 - ey * dx13;
                const bool m = (den_t * num > 0.f) & (fabsf(den_t) < fabsf(num))
                             & (den_u * num < 0.f) & (fabsf(den_u) < fabsf(num));
                const float t2 = den_t * rcpf(num + 1e-8f);   // reference quirk
                const float ix = fmaf(t2, ex, x1), iy = fmaf(t2, ey, y1);
                const int s = 8 + a * 4 + b;
                s_v[s * BS + tid] = make_float2(ix, iy);   // garbage if invalid:
                if (m) { vm |= 1u << s; sx += ix; sy += iy; k++; }   // never read
            }
        }

        // ---- keys: quantized monotone-u32(pseudo-angle) | slot-idx ----
        const float kf = (float)(k > 0 ? k : 1);
        const float mx = sx / kf, my = sy / kf;
        unsigned key[NS];
#pragma unroll
        for (int s = 0; s < NS; s++) {
            const float2 v = s_v[s * BS + tid];
            const float dx = v.x - mx, dy = v.y - my;
            const float sa = fabsf(dx) + fabsf(dy);
            float ang = copysignf(1.f - dx * rcpf(sa), dy);  // order == atan2 order
            ang = (sa == 0.f) ? 0.f : ang;
            ang = ((vm >> s) & 1u) ? ang : 1e9f;             // invalid -> back
            unsigned bb = __float_as_uint(ang);
            bb ^= (unsigned)((int)bb >> 31) | 0x80000000u;   // monotone map
            key[s] = (bb & 0xFFFFFFE0u) | (unsigned)s;       // idx = stable tiebreak
        }

        // ---- Batcher merge-exchange network, n=24 (127 comparators), keys only ----
        // p=16
        CSWAPK(0,16); CSWAPK(1,17); CSWAPK(2,18); CSWAPK(3,19);
        CSWAPK(4,20); CSWAPK(5,21); CSWAPK(6,22); CSWAPK(7,23);
        // p=8
        CSWAPK(0,8);  CSWAPK(1,9);  CSWAPK(2,10); CSWAPK(3,11);
        CSWAPK(4,12); CSWAPK(5,13); CSWAPK(6,14); CSWAPK(7,15);
        CSWAPK(8,16); CSWAPK(9,17); CSWAPK(10,18); CSWAPK(11,19);
        CSWAPK(12,20); CSWAPK(13,21); CSWAPK(14,22); CSWAPK(15,23);
        // p=4
        CSWAPK(0,4);  CSWAPK(1,5);  CSWAPK(2,6);  CSWAPK(3,7);
        CSWAPK(8,12); CSWAPK(9,13); CSWAPK(10,14); CSWAPK(11,15);
        CSWAPK(16,20); CSWAPK(17,21); CSWAPK(18,22); CSWAPK(19,23);
        CSWAPK(4,16); CSWAPK(5,17); CSWAPK(6,18); CSWAPK(7,19);
        CSWAPK(4,8);  CSWAPK(5,9);  CSWAPK(6,10); CSWAPK(7,11);
        CSWAPK(12,16); CSWAPK(13,17); CSWAPK(14,18); CSWAPK(15,19);
        // p=2
        CSWAPK(0,2);  CSWAPK(1,3);  CSWAPK(4,6);  CSWAPK(5,7);
        CSWAPK(8,10); CSWAPK(9,11); CSWAPK(12,14); CSWAPK(13,15);
        CSWAPK(16,18); CSWAPK(17,19); CSWAPK(20,22); CSWAPK(21,23);
        CSWAPK(2,16); CSWAPK(3,17); CSWAPK(6,20); CSWAPK(7,21);
        CSWAPK(2,8);  CSWAPK(3,9);  CSWAPK(6,12); CSWAPK(7,13);
        CSWAPK(10,16); CSWAPK(11,17); CSWAPK(14,20); CSWAPK(15,21);
        CSWAPK(2,4);  CSWAPK(3,5);  CSWAPK(6,8);  CSWAPK(7,9);
        CSWAPK(10,12); CSWAPK(11,13); CSWAPK(14,16); CSWAPK(15,17);
        CSWAPK(18,20); CSWAPK(19,21);
        // p=1
        CSWAPK(0,1);  CSWAPK(2,3);  CSWAPK(4,5);  CSWAPK(6,7);
        CSWAPK(8,9);  CSWAPK(10,11); CSWAPK(12,13); CSWAPK(14,15);
        CSWAPK(16,17); CSWAPK(18,19); CSWAPK(20,21); CSWAPK(22,23);
        CSWAPK(1,16); CSWAPK(3,18); CSWAPK(5,20); CSWAPK(7,22);
        CSWAPK(1,8);  CSWAPK(3,10); CSWAPK(5,12); CSWAPK(7,14);
        CSWAPK(9,16); CSWAPK(11,18); CSWAPK(13,20); CSWAPK(15,22);
        CSWAPK(1,4);  CSWAPK(3,6);  CSWAPK(5,8);  CSWAPK(7,10);
        CSWAPK(9,12); CSWAPK(11,14); CSWAPK(13,16); CSWAPK(15,18);
        CSWAPK(17,20); CSWAPK(19,22);
        CSWAPK(1,2);  CSWAPK(3,4);  CSWAPK(5,6);  CSWAPK(7,8);
        CSWAPK(9,10); CSWAPK(11,12); CSWAPK(13,14); CSWAPK(15,16);
        CSWAPK(17,18); CSWAPK(19,20); CSWAPK(21,22);

        // ---- shoelace: gather coords by sorted slot-idx from LDS ----
        // k valid keys sort strictly before all invalid keys, so positions
        // j<k are exactly the valid vertices in reference order.
        float cr = 0.f, fx0 = 0.f, fy0 = 0.f, lx = 0.f, ly = 0.f;
#pragma unroll
        for (int j = 0; j < NS; j++) {
            const float2 v = s_v[(key[j] & 31u) * BS + tid];
            if (j == 0) { fx0 = v.x; fy0 = v.y; lx = v.x; ly = v.y; }
            else {
                const bool act = (j < k);
                const float c = lx * v.y - ly * v.x;
                cr += act ? c : 0.f;
                lx = act ? v.x : lx;
                ly = act ? v.y : ly;
            }
        }
        cr += lx * fy0 - ly * fx0;                      // wrap k-1 -> 0
        const float area = (k > 0) ? fabsf(cr) * 0.5f : 0.f;

        // ---- IoU + loss ----
        const float a1 = pw * ph, a2 = gw * gh;
        float iou = area / (a1 + a2 - area);
        iou = fmaxf(iou, 1e-6f);
        loss = 1.f - iou + res;
    }

    // ---- block reduction: wave shuffle -> LDS -> one atomic per block ----
#pragma unroll
    for (int off = 32; off > 0; off >>= 1)
        loss += __shfl_down(loss, off, 64);
    if ((tid & 63) == 0) s_red[tid >> 6] = loss;
    __syncthreads();
    if (tid == 0) {
        float t = 0.f;
#pragma unroll
        for (int w = 0; w < BS / 64; w++) t += s_red[w];
        atomicAdd(out, t * inv_n);
    }
}

extern "C" void kernel_launch(void* const* d_in, const int* in_sizes, int n_in,
                              void* d_out, int out_size, void* d_ws, size_t ws_size,
                              hipStream_t stream)
{
    const float* pred = (const float*)d_in[0];
    const float* tgt  = (const float*)d_in[1];
    float* out = (float*)d_out;
    const int n = in_sizes[0] / 5;
    const int nblk = (n + BS - 1) / BS;

    hipMemsetAsync(out, 0, sizeof(float), stream);   // async on stream: capturable
    fpdiou_kernel<<<nblk, BS, 0, stream>>>(pred, tgt, out, n, 1.f / (float)n);
}